// Round 1
// baseline (131.126 us; speedup 1.0000x reference)
//
#include <hip/hip_runtime.h>

#define SEQ   1024
#define BATCH 32
#define DIM   256   // 64 float4 per row

// ---------------------------------------------------------------------------
// Kernel 1: fill the per-(frame,batch) position index array with -1.
// Harness poisons d_ws with 0xAA before every launch, so we must init it.
// ---------------------------------------------------------------------------
__global__ __launch_bounds__(256) void pe_fill(int* __restrict__ pos, int n) {
    int i = blockIdx.x * blockDim.x + threadIdx.x;
    if (i < n) pos[i] = -1;
}

// ---------------------------------------------------------------------------
// Kernel 2: per-batch inclusive scan of durations (1024 tokens, 256 threads x
// 4 tokens each, LDS Hillis-Steele across threads), then scatter the frame ->
// within-token position mapping: pos[f*BATCH + b] = f - start(token).
// Every valid frame (f < total[b]) is covered by exactly one token with d>0;
// invalid tail frames stay -1.
// ---------------------------------------------------------------------------
__global__ __launch_bounds__(256) void pe_scan_scatter(const int* __restrict__ dur,
                                                       int* __restrict__ pos,
                                                       int T) {
    const int b = blockIdx.x;    // batch element, 0..31
    const int t = threadIdx.x;   // 0..255
    __shared__ int ssum[256];

    // load 4 consecutive tokens for this thread (column b, stride BATCH)
    int d[4];
    const int base = (t * 4) * BATCH + b;
#pragma unroll
    for (int i = 0; i < 4; ++i) d[i] = dur[base + i * BATCH];

    ssum[t] = d[0] + d[1] + d[2] + d[3];
    __syncthreads();

    // Hillis-Steele inclusive scan over the 256 per-thread sums
    for (int off = 1; off < 256; off <<= 1) {
        int v = (t >= off) ? ssum[t - off] : 0;
        __syncthreads();
        ssum[t] += v;
        __syncthreads();
    }

    int start = (t > 0) ? ssum[t - 1] : 0;   // exclusive prefix for token 4t
#pragma unroll
    for (int i = 0; i < 4; ++i) {
        for (int k = 0; k < d[i]; ++k) {     // d[i] in [0, 8)
            int f = start + k;
            if (f < T) pos[f * BATCH + b] = k;
        }
        start += d[i];
    }
}

// ---------------------------------------------------------------------------
// Kernel 3: gather. One float4 (16B) per thread, fully coalesced writes.
// Only encoding rows 0..7 are ever touched (dur < 8) -> L1-resident reads.
// ---------------------------------------------------------------------------
__global__ __launch_bounds__(256) void pe_gather(const int* __restrict__ pos,
                                                 const float4* __restrict__ enc,
                                                 float4* __restrict__ out,
                                                 int n4) {
    int idx = blockIdx.x * blockDim.x + threadIdx.x;
    if (idx >= n4) return;
    int row = idx >> 6;          // (frame, batch) row
    int c   = idx & 63;          // float4 column within DIM
    int p   = pos[row];
    float4 v;
    if (p >= 0) {
        v = enc[p * (DIM / 4) + c];
    } else {
        v.x = 0.f; v.y = 0.f; v.z = 0.f; v.w = 0.f;
    }
    out[idx] = v;
}

extern "C" void kernel_launch(void* const* d_in, const int* in_sizes, int n_in,
                              void* d_out, int out_size, void* d_ws, size_t ws_size,
                              hipStream_t stream) {
    const int*   dur = (const int*)d_in[0];     // (SEQ, BATCH) int32
    const float* enc = (const float*)d_in[1];   // (1000, DIM) float32
    float*       out = (float*)d_out;           // (T, BATCH, DIM) float32

    const int T     = out_size / (BATCH * DIM); // harness gives flat out elems
    const int nrows = T * BATCH;                // pos array size (ints)
    int* pos = (int*)d_ws;

    pe_fill<<<(nrows + 255) / 256, 256, 0, stream>>>(pos, nrows);
    pe_scan_scatter<<<BATCH, 256, 0, stream>>>(dur, pos, T);

    const int n4 = nrows * (DIM / 4);
    pe_gather<<<(n4 + 255) / 256, 256, 0, stream>>>(
        pos, (const float4*)enc, (float4*)out, n4);
}